// Round 14
// baseline (424.055 us; speedup 1.0000x reference)
//
#include <hip/hip_runtime.h>
#include <hip/hip_bf16.h>
#include <stdint.h>

#define NB 32
#define NC 512
#define NP 576
#define NN 4096
#define APANEL8 294912u  // NP*NC bytes (fp8)
#define ATILE8 18432u    // NP*32 bytes per k-tile
#define XPB 2097152u     // per-batch Xp bytes (512*4096 fp8)
#define LOG2E 1.44269504088896340736f

typedef __attribute__((ext_vector_type(4))) float floatx4;

// ---------------- K1: inverse L2 norms over channel dim (patch only) ----------------
__global__ void norms_kernel(const float* __restrict__ in, float* __restrict__ invn,
                             int nsp, int total) {
  int idx = blockIdx.x * 256 + threadIdx.x;
  if (idx >= total) return;
  int b = idx / nsp, sp = idx - b * nsp;
  const float* p = in + (size_t)b * NC * nsp + sp;
  float s = 0.f;
#pragma unroll 8
  for (int c = 0; c < NC; ++c) { float v = p[(size_t)c * nsp]; s = fmaf(v, v, s); }
  invn[idx] = 1.0f / fmaxf(sqrtf(s), 1e-12f);
}

// ---------------- K2: patch [C][P] -> fp8 fragment-tiled A2, scale ----------------
// A2 byte = b*APANEL8 + kt*ATILE8 + (p>>4)*512 + g*128 + (p&15)*8 + e,
// holding c = kt*32 + g*8 + e for row p.
__global__ void transpose_kernel(const float* __restrict__ in, const float* __restrict__ invn,
                                 uint8_t* __restrict__ out, int nsp) {
  __shared__ float tile[64][65];
  int b = blockIdx.z, c0 = blockIdx.y * 64, p0 = blockIdx.x * 64;
  int tx = threadIdx.x & 63, ty = threadIdx.x >> 6;
  const float* src = in + ((size_t)b * NC + c0) * nsp + p0;
#pragma unroll
  for (int r = ty; r < 64; r += 4) tile[r][tx] = src[(size_t)r * nsp + tx];
  __syncthreads();
  int p = p0 + tx;
  float iv = invn[b * nsp + p];
  char* dst = (char*)out + (size_t)b * APANEL8
            + (uint32_t)(p >> 4) * 512u + (uint32_t)(p & 15) * 8u;
#pragma unroll
  for (int q = ty; q < 8; q += 4) {
    int c_local = q * 8, c_global = c0 + c_local;
    float f[8];
#pragma unroll
    for (int e = 0; e < 8; ++e) f[e] = tile[c_local + e][tx] * iv;
    int lo = 0, hi = 0;
    lo = __builtin_amdgcn_cvt_pk_fp8_f32(f[0], f[1], lo, false);
    lo = __builtin_amdgcn_cvt_pk_fp8_f32(f[2], f[3], lo, true);
    hi = __builtin_amdgcn_cvt_pk_fp8_f32(f[4], f[5], hi, false);
    hi = __builtin_amdgcn_cvt_pk_fp8_f32(f[6], f[7], hi, true);
    union { int i2[2]; long l; } u; u.i2[0] = lo; u.i2[1] = hi;
    uint32_t kt = (uint32_t)c_global >> 5, gg = ((uint32_t)c_global >> 3) & 3u;
    *(long*)(dst + kt * ATILE8 + gg * 128u) = u.l;
  }
}

// ---------------- K2b: pack x fp32 -> Xp fp8 in GEMM-fragment layout + sumsq ----
// Xp byte = b*XPB + (j>>6)*32768 + kt*2048 + g*512 + (j&63)*8 + e,
// holding c = kt*32 + g*8 + e for column j. part[b][kt][j] = sumsq over 32 c.
__global__ __launch_bounds__(256) void pack_kernel(const float* __restrict__ x,
                                                   uint8_t* __restrict__ Xp,
                                                   float* __restrict__ part) {
  const int bid = blockIdx.x;                 // 2048 = 32 b * 16 kt * 4 jq
  const int b = bid >> 6, kt = (bid >> 2) & 15, jq = bid & 3;
  const int tid = threadIdx.x;
  const float* xb = x + ((size_t)(b * NC + kt * 32) * NN);
  char* xpb = (char*)Xp + (size_t)b * XPB + (uint32_t)kt * 2048u;
#pragma unroll 1
  for (int i = 0; i < 4; ++i) {
    int j = (jq * 4 + i) * 256 + tid;
    float v[4][8];
#pragma unroll
    for (int g = 0; g < 4; ++g)
#pragma unroll
      for (int e = 0; e < 8; ++e)
        v[g][e] = xb[(size_t)(g * 8 + e) * NN + j];
    float sq = 0.f;
#pragma unroll
    for (int g = 0; g < 4; ++g) {
#pragma unroll
      for (int e = 0; e < 8; ++e) sq = fmaf(v[g][e], v[g][e], sq);
      int lo = 0, hi = 0;
      lo = __builtin_amdgcn_cvt_pk_fp8_f32(v[g][0], v[g][1], lo, false);
      lo = __builtin_amdgcn_cvt_pk_fp8_f32(v[g][2], v[g][3], lo, true);
      hi = __builtin_amdgcn_cvt_pk_fp8_f32(v[g][4], v[g][5], hi, false);
      hi = __builtin_amdgcn_cvt_pk_fp8_f32(v[g][6], v[g][7], hi, true);
      union { int i2[2]; long l; } u; u.i2[0] = lo; u.i2[1] = hi;
      *(long*)(xpb + (uint32_t)(j >> 6) * 32768u + (uint32_t)g * 512u
               + (uint32_t)(j & 63) * 8u) = u.l;
    }
    part[((b * 16 + kt) * 4096) + j] = sq;
  }
}

// ---------------- K2c: invd[b][j] = rsqrt(sum_kt part) * log2e ----------------
__global__ void invd_kernel(const float* __restrict__ part, float* __restrict__ invd) {
  int t = blockIdx.x * 256 + threadIdx.x;     // 32*4096
  int b = t >> 12, j = t & 4095;
  float s = 0.f;
#pragma unroll
  for (int kt = 0; kt < 16; ++kt) s += part[(b * 16 + kt) * 4096 + j];
  invd[t] = rsqrtf(fmaxf(s, 1e-24f)) * LOG2E;
}

// ---------------- K3: GEMM + softmax-reduction — one INDEPENDENT wave/block ----
// 2048 blocks x 64 thr, 3 waves/SIMD (12 independent blocks/CU). No barriers,
// no LDS, plain-C loads (compiler-managed waits: spill-safe). Per wave:
// 6 chunks x 96 rows (acc[6][4] = 96 AGPR), per k-step 6 A-b64 (L2-hot) +
// 4 B-b64 (Xp via L3) + 24 MFMA. TLP across the 12 waves/CU hides latency.
__global__ __launch_bounds__(64, 3)
void affinity_kernel(const uint8_t* __restrict__ A2,
                     const uint8_t* __restrict__ Xp,
                     const float* __restrict__ invd,
                     float* __restrict__ partials) {
  const int bid = blockIdx.x;
  const int T = (bid & 7) * 256 + (bid >> 3);   // bijective XCD swizzle (2048 = 8*256)
  const int b = T >> 6, jc = T & 63;
  const int lane = threadIdx.x;
  const int g = lane >> 4, l15 = lane & 15;

  const char* Ab = (const char*)A2 + (size_t)b * APANEL8 + (uint32_t)lane * 8u;
  const char* Xb = (const char*)Xp + (size_t)b * XPB + (uint32_t)jc * 32768u
                 + (uint32_t)g * 512u + (uint32_t)l15 * 8u;

  float iv[4];
#pragma unroll
  for (int q = 0; q < 4; ++q)
    iv[q] = invd[b * 4096 + jc * 64 + q * 16 + l15];
  const float cxbase = (float)l15 + 0.5f;   // cx = q*16 + l15 + 0.5

#pragma unroll 1
  for (int c = 0; c < 6; ++c) {
    asm volatile("" ::: "memory");   // block LICM from hoisting B loads across chunks
    floatx4 acc[6][4];
#pragma unroll
    for (int mi = 0; mi < 6; ++mi)
#pragma unroll
      for (int q = 0; q < 4; ++q) acc[mi][q] = (floatx4){0.f, 0.f, 0.f, 0.f};

#pragma unroll
    for (int kt = 0; kt < 16; ++kt) {
      long a6[6], b4[4];
#pragma unroll
      for (int mi = 0; mi < 6; ++mi)
        a6[mi] = *(const long*)(Ab + (uint32_t)kt * ATILE8 + (uint32_t)(c * 6 + mi) * 512u);
#pragma unroll
      for (int q = 0; q < 4; ++q)
        b4[q] = *(const long*)(Xb + (uint32_t)kt * 2048u + (uint32_t)q * 128u);
#pragma unroll
      for (int q = 0; q < 4; ++q)
#pragma unroll
        for (int mi = 0; mi < 6; ++mi)
          acc[mi][q] = __builtin_amdgcn_mfma_f32_16x16x32_fp8_fp8(a6[mi], b4[q], acc[mi][q], 0, 0, 0);
    }

    // ---- epilogue for chunk c (cy = jc + 0.5 handled in finalize) ----
#pragma unroll
    for (int mi = 0; mi < 6; ++mi) {
      float s4[4] = {0.f, 0.f, 0.f, 0.f}, sx4[4] = {0.f, 0.f, 0.f, 0.f};
#pragma unroll
      for (int q = 0; q < 4; ++q) {
        float cx = (float)(q * 16) + cxbase;
#pragma unroll
        for (int r = 0; r < 4; ++r) {
          float p = exp2f(acc[mi][q][r] * iv[q]);
          s4[r] += p;
          sx4[r] = fmaf(p, cx, sx4[r]);
        }
      }
#pragma unroll
      for (int r = 0; r < 4; ++r) {
#pragma unroll
        for (int m = 1; m < 16; m <<= 1) {
          s4[r] += __shfl_xor(s4[r], m);
          sx4[r] += __shfl_xor(sx4[r], m);
        }
      }
      if (l15 == 0) {
#pragma unroll
        for (int r = 0; r < 4; ++r) {
          int row = (c * 6 + mi) * 16 + g * 4 + r;
          float2 o2 = make_float2(s4[r], sx4[r]);
          *(float2*)(partials + ((size_t)(b * NP + row) * 64 + jc) * 2) = o2;
        }
      }
    }
  }
}

// ---------------- K4: finalize ----------------
__global__ void finalize_kernel(const float* __restrict__ partials, float* __restrict__ out) {
  int b = blockIdx.x;
  int t = threadIdx.x;
  float sxt = 0.f, syt = 0.f;
  for (int i = t; i < NP; i += 256) {
    const float* p = partials + ((size_t)(b * NP + i) * 64) * 2;
    float s = 0.f, sx = 0.f, sy = 0.f;
#pragma unroll
    for (int jc2 = 0; jc2 < 64; ++jc2) {
      float ss = p[jc2 * 2];
      s += ss;
      sx += p[jc2 * 2 + 1];
      sy = fmaf(ss, (float)jc2 + 0.5f, sy);
    }
    sxt += sx / s;
    syt += sy / s;
  }
  __shared__ float rs[256], rs2[256];
  rs[t] = sxt; rs2[t] = syt;
  __syncthreads();
  for (int o = 128; o > 0; o >>= 1) {
    if (t < o) { rs[t] += rs[t + o]; rs2[t] += rs2[t + o]; }
    __syncthreads();
  }
  if (t == 0) {
    float cx = rs[0] / (float)NP, cy = rs2[0] / (float)NP;
    float l = fmaxf(cx - 12.f, 0.f);
    float tp = fmaxf(cy - 12.f, 0.f);
    out[b * 4 + 0] = l;
    out[b * 4 + 1] = tp;
    out[b * 4 + 2] = fminf(l + 24.f, 64.f);
    out[b * 4 + 3] = fminf(tp + 24.f, 64.f);
  }
}

extern "C" void kernel_launch(void* const* d_in, const int* in_sizes, int n_in,
                              void* d_out, int out_size, void* d_ws, size_t ws_size,
                              hipStream_t stream) {
  const float* patch_x = (const float*)d_in[0];
  const float* x = (const float*)d_in[1];
  float* out = (float*)d_out;
  char* ws = (char*)d_ws;

  float* inv_src = (float*)(ws + 0);                  //     73,728 B
  uint8_t* A2 = (uint8_t*)(ws + 73728);               //  9,437,184 B (fp8)
  uint8_t* Xp = (uint8_t*)(ws + 9510912);             // 67,108,864 B (fp8)
  float* part = (float*)(ws + 76619776);              //  8,388,608 B
  float* invd = (float*)(ws + 85008384);              //    524,288 B
  float* partials = (float*)(ws + 85532672);          //  9,437,184 B  (end ~95 MB)

  norms_kernel<<<dim3((NB * NP + 255) / 256), 256, 0, stream>>>(patch_x, inv_src, NP, NB * NP);
  transpose_kernel<<<dim3(NP / 64, NC / 64, NB), 256, 0, stream>>>(patch_x, inv_src, A2, NP);
  pack_kernel<<<dim3(2048), 256, 0, stream>>>(x, Xp, part);
  invd_kernel<<<dim3(512), 256, 0, stream>>>(part, invd);
  affinity_kernel<<<dim3(NB * 64), 64, 0, stream>>>(A2, Xp, invd, partials);
  finalize_kernel<<<NB, 256, 0, stream>>>(partials, out);
}

// Round 16
// 206.663 us; speedup vs baseline: 2.0519x; 2.0519x over previous
//
#include <hip/hip_runtime.h>
#include <hip/hip_bf16.h>
#include <stdint.h>

#define NB 32
#define NC 512
#define NP 576
#define NN 4096
#define APANEL8 294912u  // NP*NC bytes (fp8)
#define ATILE8 18432u    // NP*32 bytes per k-tile
#define LOG2E 1.44269504088896340736f

typedef __attribute__((ext_vector_type(4))) float floatx4;

// ---------------- K1: inverse L2 norms over channel dim (patch only) ----------------
__global__ void norms_kernel(const float* __restrict__ in, float* __restrict__ invn,
                             int nsp, int total) {
  int idx = blockIdx.x * 256 + threadIdx.x;
  if (idx >= total) return;
  int b = idx / nsp, sp = idx - b * nsp;
  const float* p = in + (size_t)b * NC * nsp + sp;
  float s = 0.f;
#pragma unroll 8
  for (int c = 0; c < NC; ++c) { float v = p[(size_t)c * nsp]; s = fmaf(v, v, s); }
  invn[idx] = 1.0f / fmaxf(sqrtf(s), 1e-12f);
}

// ---------------- K2: patch [C][P] -> fp8 fragment-tiled A2, scale ----------------
// A2 byte = b*APANEL8 + kt*ATILE8 + (p>>4)*512 + g*128 + (p&15)*8 + e,
// holding c = kt*32 + g*8 + e for row p.
__global__ void transpose_kernel(const float* __restrict__ in, const float* __restrict__ invn,
                                 uint8_t* __restrict__ out, int nsp) {
  __shared__ float tile[64][65];
  int b = blockIdx.z, c0 = blockIdx.y * 64, p0 = blockIdx.x * 64;
  int tx = threadIdx.x & 63, ty = threadIdx.x >> 6;
  const float* src = in + ((size_t)b * NC + c0) * nsp + p0;
#pragma unroll
  for (int r = ty; r < 64; r += 4) tile[r][tx] = src[(size_t)r * nsp + tx];
  __syncthreads();
  int p = p0 + tx;
  float iv = invn[b * nsp + p];
  char* dst = (char*)out + (size_t)b * APANEL8
            + (uint32_t)(p >> 4) * 512u + (uint32_t)(p & 15) * 8u;
#pragma unroll
  for (int q = ty; q < 8; q += 4) {
    int c_local = q * 8, c_global = c0 + c_local;
    float f[8];
#pragma unroll
    for (int e = 0; e < 8; ++e) f[e] = tile[c_local + e][tx] * iv;
    int lo = 0, hi = 0;
    lo = __builtin_amdgcn_cvt_pk_fp8_f32(f[0], f[1], lo, false);
    lo = __builtin_amdgcn_cvt_pk_fp8_f32(f[2], f[3], lo, true);
    hi = __builtin_amdgcn_cvt_pk_fp8_f32(f[4], f[5], hi, false);
    hi = __builtin_amdgcn_cvt_pk_fp8_f32(f[6], f[7], hi, true);
    union { int i2[2]; long l; } u; u.i2[0] = lo; u.i2[1] = hi;
    uint32_t kt = (uint32_t)c_global >> 5, gg = ((uint32_t)c_global >> 3) & 3u;
    *(long*)(dst + kt * ATILE8 + gg * 128u) = u.l;
  }
}

// ---------------- K3: fused pack + GEMM + softmax-reduction ----------------
// 4096 blocks (32 b x 128 jc of 32 cols), 256 thr / 4 waves, 3 blocks/CU.
// Full-M (576) per block: x read EXACTLY ONCE. Per step: threads stage 4 fp32,
// cvt_pk -> one ds_write_b32 into fragment-layout LDS (double-buffered, 2KB);
// wave w computes 144 rows (acc[9][2] = 72 AGPR). Plain-C loads only
// (compiler-managed waits, spill-safe); 1 barrier/step; de-phasing via 3
// independent blocks/CU hides both HBM and L2 latency (m114 overlap).
__global__ __launch_bounds__(256, 3)
void affinity_kernel(const uint8_t* __restrict__ A2,
                     const float* __restrict__ x,
                     float* __restrict__ partials) {
  const int bid = blockIdx.x;
  const int T = (bid & 7) * 512 + (bid >> 3);   // bijective XCD swizzle (4096 = 8*512)
  const int b = T >> 7, jc = T & 127;
  const int tid = threadIdx.x, lane = tid & 63, w = tid >> 6;
  const int g = lane >> 4, l15 = lane & 15;
  const int sj = tid & 31, rgrp = tid >> 5;     // staging: col sj, row-group rgrp

  __shared__ __align__(16) char Bsh[2][2048];
  __shared__ float red[8][32];
  __shared__ float invd[32];

  const char* Ab = (const char*)A2 + (size_t)b * APANEL8
                 + (uint32_t)(w * 9) * 512u + (uint32_t)lane * 8u;
  const float* xb = x + (size_t)(b * NC + rgrp * 4) * NN + jc * 32 + sj;

  floatx4 acc[9][2];
#pragma unroll
  for (int mi = 0; mi < 9; ++mi)
#pragma unroll
    for (int q = 0; q < 2; ++q) acc[mi][q] = (floatx4){0.f, 0.f, 0.f, 0.f};

  float sq = 0.f;

  auto loadX = [&](int kt, float (&v)[4]) {
#pragma unroll
    for (int i = 0; i < 4; ++i)
      v[i] = xb[(size_t)(kt * 32 + i) * NN];
  };
  auto cvtWrite = [&](float (&v)[4], int buf) {
#pragma unroll
    for (int i = 0; i < 4; ++i) sq = fmaf(v[i], v[i], sq);
    int d = 0;
    d = __builtin_amdgcn_cvt_pk_fp8_f32(v[0], v[1], d, false);
    d = __builtin_amdgcn_cvt_pk_fp8_f32(v[2], v[3], d, true);
    *(int*)(Bsh[buf] + (uint32_t)(rgrp >> 1) * 256u + (uint32_t)sj * 8u
            + (uint32_t)(rgrp & 1) * 4u) = d;
  };
  auto mfmaStep = [&](int buf, int kt) {
    long a9[9];
#pragma unroll
    for (int mi = 0; mi < 9; ++mi)
      a9[mi] = *(const long*)(Ab + (uint32_t)kt * ATILE8 + (uint32_t)mi * 512u);
    __builtin_amdgcn_s_setprio(1);
#pragma unroll
    for (int q = 0; q < 2; ++q) {
      long bf = *(const long*)(Bsh[buf] + (uint32_t)g * 256u
                               + (uint32_t)(q * 16 + l15) * 8u);
#pragma unroll
      for (int mi = 0; mi < 9; ++mi)
        acc[mi][q] = __builtin_amdgcn_mfma_f32_16x16x32_fp8_fp8(a9[mi], bf, acc[mi][q], 0, 0, 0);
    }
    __builtin_amdgcn_s_setprio(0);
  };

  // ---- prologue: stage tile 0 ----
  float v0[4], v1[4];
  loadX(0, v0);
  cvtWrite(v0, 0);
  __syncthreads();

  // ---- main loop: 16 k-steps, double-buffered, 1 barrier/step ----
#pragma unroll 2
  for (int kt = 0; kt < 16; ++kt) {
    if (kt < 15) {
      if (kt & 1) loadX(kt + 1, v0); else loadX(kt + 1, v1);
    }
    mfmaStep(kt & 1, kt);
    if (kt < 15) {
      if (kt & 1) cvtWrite(v0, (kt + 1) & 1); else cvtWrite(v1, (kt + 1) & 1);
    }
    __syncthreads();
  }

  // ---- dst inv-norms (col j = jc*32 + sj) ----
  red[rgrp][sj] = sq;
  __syncthreads();
  if (tid < 32) {
    float s = 0.f;
#pragma unroll
    for (int r = 0; r < 8; ++r) s += red[r][tid];
    invd[tid] = rsqrtf(fmaxf(s, 1e-24f)) * LOG2E;
  }
  __syncthreads();

  float iv[2], cxj[2];
#pragma unroll
  for (int q = 0; q < 2; ++q) {
    iv[q] = invd[q * 16 + l15];
    cxj[q] = (float)((jc & 1) * 32 + q * 16 + l15) + 0.5f;  // cx = j & 63 + .5
  }

  // ---- epilogue: exp2 + weighted reduce (cy = (jc>>1)+0.5 in finalize) ----
#pragma unroll
  for (int mi = 0; mi < 9; ++mi) {
    float s4[4] = {0.f, 0.f, 0.f, 0.f}, sx4[4] = {0.f, 0.f, 0.f, 0.f};
#pragma unroll
    for (int q = 0; q < 2; ++q)
#pragma unroll
      for (int r = 0; r < 4; ++r) {
        float p = exp2f(acc[mi][q][r] * iv[q]);
        s4[r] += p;
        sx4[r] = fmaf(p, cxj[q], sx4[r]);
      }
#pragma unroll
    for (int r = 0; r < 4; ++r) {
#pragma unroll
      for (int m = 1; m < 16; m <<= 1) {
        s4[r] += __shfl_xor(s4[r], m);
        sx4[r] += __shfl_xor(sx4[r], m);
      }
    }
    if (l15 == 0) {
#pragma unroll
      for (int r = 0; r < 4; ++r) {
        int row = w * 144 + mi * 16 + g * 4 + r;
        float2 o2 = make_float2(s4[r], sx4[r]);
        *(float2*)(partials + ((size_t)(b * NP + row) * 128 + jc) * 2) = o2;
      }
    }
  }
}

// ---------------- K4: finalize ----------------
__global__ void finalize_kernel(const float* __restrict__ partials, float* __restrict__ out) {
  int b = blockIdx.x;
  int t = threadIdx.x;
  float sxt = 0.f, syt = 0.f;
  for (int i = t; i < NP; i += 256) {
    const float* p = partials + ((size_t)(b * NP + i) * 128) * 2;
    float s = 0.f, sx = 0.f, sy = 0.f;
#pragma unroll
    for (int jc2 = 0; jc2 < 128; ++jc2) {
      float ss = p[jc2 * 2];
      s += ss;
      sx += p[jc2 * 2 + 1];
      sy = fmaf(ss, (float)(jc2 >> 1) + 0.5f, sy);   // cy = (j>>6)+0.5, j = jc2*32+l
    }
    sxt += sx / s;
    syt += sy / s;
  }
  __shared__ float rs[256], rs2[256];
  rs[t] = sxt; rs2[t] = syt;
  __syncthreads();
  for (int o = 128; o > 0; o >>= 1) {
    if (t < o) { rs[t] += rs[t + o]; rs2[t] += rs2[t + o]; }
    __syncthreads();
  }
  if (t == 0) {
    float cx = rs[0] / (float)NP, cy = rs2[0] / (float)NP;
    float l = fmaxf(cx - 12.f, 0.f);
    float tp = fmaxf(cy - 12.f, 0.f);
    out[b * 4 + 0] = l;
    out[b * 4 + 1] = tp;
    out[b * 4 + 2] = fminf(l + 24.f, 64.f);
    out[b * 4 + 3] = fminf(tp + 24.f, 64.f);
  }
}

extern "C" void kernel_launch(void* const* d_in, const int* in_sizes, int n_in,
                              void* d_out, int out_size, void* d_ws, size_t ws_size,
                              hipStream_t stream) {
  const float* patch_x = (const float*)d_in[0];
  const float* x = (const float*)d_in[1];
  float* out = (float*)d_out;
  char* ws = (char*)d_ws;

  float* inv_src = (float*)(ws + 0);                  //     73,728 B
  uint8_t* A2 = (uint8_t*)(ws + 73728);               //  9,437,184 B (fp8)
  float* partials = (float*)(ws + 9510912);           // 18,874,368 B  (end ~28.4 MB)

  norms_kernel<<<dim3((NB * NP + 255) / 256), 256, 0, stream>>>(patch_x, inv_src, NP, NB * NP);
  transpose_kernel<<<dim3(NP / 64, NC / 64, NB), 256, 0, stream>>>(patch_x, inv_src, A2, NP);
  affinity_kernel<<<dim3(4096), 256, 0, stream>>>(A2, x, partials);
  finalize_kernel<<<NB, 256, 0, stream>>>(partials, out);
}

// Round 19
// 162.749 us; speedup vs baseline: 2.6056x; 1.2698x over previous
//
#include <hip/hip_runtime.h>
#include <hip/hip_bf16.h>
#include <stdint.h>

#define NB 32
#define NC 512
#define NP 576
#define NN 4096
#define APANEL8 294912u  // NP*NC bytes (fp8)
#define ATILE8 18432u    // NP*32 bytes per k-tile
#define LOG2E 1.44269504088896340736f

typedef __attribute__((ext_vector_type(4))) float floatx4;

#define GLOAD_F32(dst, voff, sbase) \
  asm volatile("global_load_dword %0, %1, %2" : "=v"(dst) : "v"(voff), "s"(sbase))
#define GLOAD_B64(dst, voff, sbase) \
  asm volatile("global_load_dwordx2 %0, %1, %2" : "=v"(dst) : "v"(voff), "s"(sbase))
#define DSWRITE_B64(addr, data) \
  asm volatile("ds_write_b64 %0, %1" :: "v"(addr), "v"(data) : "memory")
#define WAIT_VMCNT(N) asm volatile("s_waitcnt vmcnt(" #N ")" ::: "memory")
#define WAIT_LGKM0    asm volatile("s_waitcnt lgkmcnt(0)" ::: "memory")
#define SBAR() do { asm volatile("" ::: "memory"); __builtin_amdgcn_s_barrier(); asm volatile("" ::: "memory"); } while (0)
#define SCHEDBAR() __builtin_amdgcn_sched_barrier(0)

// ---------------- K1: inverse L2 norms over channel dim (patch only) ----------------
__global__ void norms_kernel(const float* __restrict__ in, float* __restrict__ invn,
                             int nsp, int total) {
  int idx = blockIdx.x * 256 + threadIdx.x;
  if (idx >= total) return;
  int b = idx / nsp, sp = idx - b * nsp;
  const float* p = in + (size_t)b * NC * nsp + sp;
  float s = 0.f;
#pragma unroll 8
  for (int c = 0; c < NC; ++c) { float v = p[(size_t)c * nsp]; s = fmaf(v, v, s); }
  invn[idx] = 1.0f / fmaxf(sqrtf(s), 1e-12f);
}

// ---------------- K2: patch [C][P] -> fp8 fragment-tiled A2, scale ----------------
// A2 byte = b*APANEL8 + kt*ATILE8 + (p>>4)*512 + g*128 + (p&15)*8 + e,
// holding c = kt*32 + g*8 + e for row p.
__global__ void transpose_kernel(const float* __restrict__ in, const float* __restrict__ invn,
                                 uint8_t* __restrict__ out, int nsp) {
  __shared__ float tile[64][65];
  int b = blockIdx.z, c0 = blockIdx.y * 64, p0 = blockIdx.x * 64;
  int tx = threadIdx.x & 63, ty = threadIdx.x >> 6;
  const float* src = in + ((size_t)b * NC + c0) * nsp + p0;
#pragma unroll
  for (int r = ty; r < 64; r += 4) tile[r][tx] = src[(size_t)r * nsp + tx];
  __syncthreads();
  int p = p0 + tx;
  float iv = invn[b * nsp + p];
  char* dst = (char*)out + (size_t)b * APANEL8
            + (uint32_t)(p >> 4) * 512u + (uint32_t)(p & 15) * 8u;
#pragma unroll
  for (int q = ty; q < 8; q += 4) {
    int c_local = q * 8, c_global = c0 + c_local;
    float f[8];
#pragma unroll
    for (int e = 0; e < 8; ++e) f[e] = tile[c_local + e][tx] * iv;
    int lo = 0, hi = 0;
    lo = __builtin_amdgcn_cvt_pk_fp8_f32(f[0], f[1], lo, false);
    lo = __builtin_amdgcn_cvt_pk_fp8_f32(f[2], f[3], lo, true);
    hi = __builtin_amdgcn_cvt_pk_fp8_f32(f[4], f[5], hi, false);
    hi = __builtin_amdgcn_cvt_pk_fp8_f32(f[6], f[7], hi, true);
    union { int i2[2]; long l; } u; u.i2[0] = lo; u.i2[1] = hi;
    uint32_t kt = (uint32_t)c_global >> 5, gg = ((uint32_t)c_global >> 3) & 3u;
    *(long*)(dst + kt * ATILE8 + gg * 128u) = u.l;
  }
}

// ---------------- K3: fused pack + GEMM + softmax-reduction ----------------
// 1024 blocks (32 b x 32 jc of 128 cols), 512 thr / 8 waves.
// Per k-step: all threads reg-stage the 16KB fp32 x-tile (depth-2 GA/GB),
// cvt->fp8 -> one ds_write_b64 into 4KB fragment-layout LDS (double-buffered).
// A-frags from fragment-tiled A2 (L2-hot). One combined vmcnt(8) per step.
// x is read EXACTLY ONCE from HBM; sumsq rides the cvt.
__global__ __launch_bounds__(512, 2)
void affinity_kernel(const uint8_t* __restrict__ A2,
                     const float* __restrict__ x,
                     float* __restrict__ partials) {
  const int bid = blockIdx.x;
  const int T = (bid & 7) * 128 + (bid >> 3);   // bijective XCD swizzle (1024 = 8*128)
  const int b = T >> 5, jc = T & 31;
  const int tid = threadIdx.x, lane = tid & 63, w = tid >> 6;
  const int wm = w & 3, wn = w >> 2;
  const int g = lane >> 4, l15 = lane & 15;
  const int sg = tid >> 7, jloc = tid & 127;

  __shared__ __align__(16) char Bsh[8192];   // 2 x [32k x 128j] fp8, fragment layout
  __shared__ float sqx[4][128];
  __shared__ float invd[128];

  const uint64_t sA = (uint64_t)(uintptr_t)A2;
  const uint64_t sX = (uint64_t)(uintptr_t)x;

  // X stage: thread (sg, jloc) loads c = kt*32 + sg*8 + e, col jc*128 + jloc
  const uint32_t voffX0 = (uint32_t)((b * NC + sg * 8) * NN + jc * 128 + jloc) * 4u;
  // A frags: rowgroup rg = wm*9 + mi
  uint32_t voffA[9];
#pragma unroll
  for (int mi = 0; mi < 9; ++mi)
    voffA[mi] = (uint32_t)b * APANEL8 + (uint32_t)(wm * 9 + mi) * 512u
              + (uint32_t)lane * 8u;

  const uint32_t wrbase = (uint32_t)(uintptr_t)(&Bsh[0])
                        + (uint32_t)sg * 1024u + (uint32_t)jloc * 8u;

  floatx4 acc[9][4];
#pragma unroll
  for (int mi = 0; mi < 9; ++mi)
#pragma unroll
    for (int q = 0; q < 4; ++q) acc[mi][q] = (floatx4){0.f, 0.f, 0.f, 0.f};

  float GA[8], GB[8];
  long af[9];
  float sq = 0.f;

  auto issueX = [&](int kt, float (&G)[8]) {
#pragma unroll
    for (int e = 0; e < 8; ++e)
      GLOAD_F32(G[e], voffX0 + (uint32_t)kt * 524288u + (uint32_t)e * 16384u, sX);
  };
  auto issueA = [&](int kt) {
#pragma unroll
    for (int mi = 0; mi < 9; ++mi)
      GLOAD_B64(af[mi], voffA[mi] + (uint32_t)kt * ATILE8, sA);
  };
  auto cvtW = [&](float (&G)[8], uint32_t bufoff) {
#pragma unroll
    for (int e = 0; e < 8; ++e) sq = fmaf(G[e], G[e], sq);
    int lo = 0, hi = 0;
    lo = __builtin_amdgcn_cvt_pk_fp8_f32(G[0], G[1], lo, false);
    lo = __builtin_amdgcn_cvt_pk_fp8_f32(G[2], G[3], lo, true);
    hi = __builtin_amdgcn_cvt_pk_fp8_f32(G[4], G[5], hi, false);
    hi = __builtin_amdgcn_cvt_pk_fp8_f32(G[6], G[7], hi, true);
    union { int i2[2]; long l; } u; u.i2[0] = lo; u.i2[1] = hi;
    DSWRITE_B64(wrbase + bufoff, u.l);
  };
  auto mfmaStep = [&](uint32_t bufoff) {
#pragma unroll
    for (int q = 0; q < 4; ++q) {
      long bf = *(const long*)(Bsh + bufoff + (uint32_t)g * 1024u
                               + (uint32_t)(wn * 64 + q * 16 + l15) * 8u);
#pragma unroll
      for (int mi = 0; mi < 9; ++mi)
        acc[mi][q] = __builtin_amdgcn_mfma_f32_16x16x32_fp8_fp8(af[mi], bf, acc[mi][q], 0, 0, 0);
    }
  };

  // ---- prologue: X0->GA, X1->GB, A0->af; buf0 = X0 ----
  issueX(0, GA);
  issueX(1, GB);
  issueA(0);
  WAIT_VMCNT(17); SCHEDBAR();     // X0 home; queue: X1[8] A0[9] = 17
  cvtW(GA, 0u);
  WAIT_LGKM0;
  SBAR();

  // ---- main loop: steps 0..13 (x2 unroll) ----
#pragma unroll 1
  for (int kt = 0; kt < 14; kt += 2) {
    // even step kt: consume buf0 + A(kt); cvt X(kt+1)(GB) -> buf1
    issueX(kt + 2, GA);           // queue: X(kt+1)8 A(kt)9 X(kt+2)8 = 25
    WAIT_VMCNT(8); SCHEDBAR();    // X(kt+1)+A(kt) home; X(kt+2) in flight
    mfmaStep(0u);
    issueA(kt + 1);               // queue: X(kt+2)8 A(kt+1)9 = 17
    cvtW(GB, 4096u);
    WAIT_LGKM0;
    SBAR();
    // odd step kt+1: consume buf1 + A(kt+1); cvt X(kt+2)(GA) -> buf0
    issueX(kt + 3, GB);
    WAIT_VMCNT(8); SCHEDBAR();
    mfmaStep(4096u);
    issueA(kt + 2);
    cvtW(GA, 0u);
    WAIT_LGKM0;
    SBAR();
  }
  // ---- step 14: queue [X15(8), A14(9)] ----
  WAIT_VMCNT(0); SCHEDBAR();      // X15 + A14 home
  mfmaStep(0u);
  issueA(15);
  cvtW(GB, 4096u);
  WAIT_LGKM0;
  SBAR();
  // ---- step 15 ----
  WAIT_VMCNT(0); SCHEDBAR();      // A15 home
  mfmaStep(4096u);

  // ---- dst inv-norms ----
  sqx[sg][jloc] = sq;
  __syncthreads();
  if (tid < 128)
    invd[tid] = rsqrtf(fmaxf(sqx[0][tid] + sqx[1][tid] + sqx[2][tid] + sqx[3][tid],
                             1e-24f)) * LOG2E;
  __syncthreads();

  // ---- epilogue: exp2 + weighted reduce; cy handled in finalize ----
  const int jcol = jc * 2 + wn;   // 64-col unit index for finalize
#pragma unroll
  for (int mi = 0; mi < 9; ++mi) {
    float s4[4] = {0.f, 0.f, 0.f, 0.f}, sx4[4] = {0.f, 0.f, 0.f, 0.f};
#pragma unroll
    for (int q = 0; q < 4; ++q) {
      float ivq = invd[wn * 64 + q * 16 + l15];
      float cx = (float)(q * 16 + l15) + 0.5f;
#pragma unroll
      for (int r = 0; r < 4; ++r) {
        float p = exp2f(acc[mi][q][r] * ivq);
        s4[r] += p;
        sx4[r] = fmaf(p, cx, sx4[r]);
      }
    }
#pragma unroll
    for (int r = 0; r < 4; ++r) {
#pragma unroll
      for (int m = 1; m < 16; m <<= 1) {
        s4[r] += __shfl_xor(s4[r], m);
        sx4[r] += __shfl_xor(sx4[r], m);
      }
    }
    if (l15 == 0) {
#pragma unroll
      for (int r = 0; r < 4; ++r) {
        int row = (wm * 9 + mi) * 16 + g * 4 + r;
        float2 o2 = make_float2(s4[r], sx4[r]);
        *(float2*)(partials + ((size_t)(b * NP + row) * 64 + jcol) * 2) = o2;
      }
    }
  }
}

// ---------------- K4: finalize ----------------
__global__ void finalize_kernel(const float* __restrict__ partials, float* __restrict__ out) {
  int b = blockIdx.x;
  int t = threadIdx.x;
  float sxt = 0.f, syt = 0.f;
  for (int i = t; i < NP; i += 256) {
    const float* p = partials + ((size_t)(b * NP + i) * 64) * 2;
    float s = 0.f, sx = 0.f, sy = 0.f;
#pragma unroll
    for (int jc2 = 0; jc2 < 64; ++jc2) {
      float ss = p[jc2 * 2];
      s += ss;
      sx += p[jc2 * 2 + 1];
      sy = fmaf(ss, (float)jc2 + 0.5f, sy);
    }
    sxt += sx / s;
    syt += sy / s;
  }
  __shared__ float rs[256], rs2[256];
  rs[t] = sxt; rs2[t] = syt;
  __syncthreads();
  for (int o = 128; o > 0; o >>= 1) {
    if (t < o) { rs[t] += rs[t + o]; rs2[t] += rs2[t + o]; }
    __syncthreads();
  }
  if (t == 0) {
    float cx = rs[0] / (float)NP, cy = rs2[0] / (float)NP;
    float l = fmaxf(cx - 12.f, 0.f);
    float tp = fmaxf(cy - 12.f, 0.f);
    out[b * 4 + 0] = l;
    out[b * 4 + 1] = tp;
    out[b * 4 + 2] = fminf(l + 24.f, 64.f);
    out[b * 4 + 3] = fminf(tp + 24.f, 64.f);
  }
}

extern "C" void kernel_launch(void* const* d_in, const int* in_sizes, int n_in,
                              void* d_out, int out_size, void* d_ws, size_t ws_size,
                              hipStream_t stream) {
  const float* patch_x = (const float*)d_in[0];
  const float* x = (const float*)d_in[1];
  float* out = (float*)d_out;
  char* ws = (char*)d_ws;

  float* inv_src = (float*)(ws + 0);                  //    73,728 B
  uint8_t* A2 = (uint8_t*)(ws + 73728);               //  9,437,184 B (fp8)
  float* partials = (float*)(ws + 9510912);           //  9,437,184 B

  norms_kernel<<<dim3((NB * NP + 255) / 256), 256, 0, stream>>>(patch_x, inv_src, NP, NB * NP);
  transpose_kernel<<<dim3(NP / 64, NC / 64, NB), 256, 0, stream>>>(patch_x, inv_src, A2, NP);
  affinity_kernel<<<dim3(1024), 512, 0, stream>>>(A2, x, partials);
  finalize_kernel<<<NB, 256, 0, stream>>>(partials, out);
}

// Round 20
// 155.949 us; speedup vs baseline: 2.7192x; 1.0436x over previous
//
#include <hip/hip_runtime.h>
#include <hip/hip_bf16.h>
#include <stdint.h>

#define NB 32
#define NC 512
#define NP 576
#define NN 4096
#define APANEL8 294912u  // NP*NC bytes (fp8)
#define ATILE8 18432u    // NP*32 bytes per k-tile
#define LOG2E 1.44269504088896340736f

typedef __attribute__((ext_vector_type(4))) float floatx4;

#define GLOAD_F32(dst, voff, sbase) \
  asm volatile("global_load_dword %0, %1, %2" : "=v"(dst) : "v"(voff), "s"(sbase))
#define GLOAD_B64(dst, voff, sbase) \
  asm volatile("global_load_dwordx2 %0, %1, %2" : "=v"(dst) : "v"(voff), "s"(sbase))
#define DSWRITE_B64(addr, data) \
  asm volatile("ds_write_b64 %0, %1" :: "v"(addr), "v"(data) : "memory")
#define WAIT_VMCNT(N) asm volatile("s_waitcnt vmcnt(" #N ")" ::: "memory")
#define WAIT_LGKM0    asm volatile("s_waitcnt lgkmcnt(0)" ::: "memory")
#define SBAR() do { asm volatile("" ::: "memory"); __builtin_amdgcn_s_barrier(); asm volatile("" ::: "memory"); } while (0)
#define SCHEDBAR() __builtin_amdgcn_sched_barrier(0)

// ---------------- K2: patch [C][P] -> RAW fp8 fragment-tiled A2 + row-sumsq partials ----
// A2 byte = b*APANEL8 + kt*ATILE8 + (p>>4)*512 + g*128 + (p&15)*8 + e,
// holding c = kt*32 + g*8 + e for row p (UNSCALED; row norm applied at epilogue).
// part_sq[(b*8 + cchunk)*NP + p] = sumsq of this 64-c chunk for row p.
__global__ void transpose_kernel(const float* __restrict__ in,
                                 uint8_t* __restrict__ out,
                                 float* __restrict__ part_sq, int nsp) {
  __shared__ float tile[64][65];
  __shared__ float red[4][64];
  int b = blockIdx.z, c0 = blockIdx.y * 64, p0 = blockIdx.x * 64;
  int tx = threadIdx.x & 63, ty = threadIdx.x >> 6;
  const float* src = in + ((size_t)b * NC + c0) * nsp + p0;
#pragma unroll
  for (int r = ty; r < 64; r += 4) tile[r][tx] = src[(size_t)r * nsp + tx];
  __syncthreads();
  // partial row-sumsq over this block's 64 c's
  {
    float s = 0.f;
#pragma unroll
    for (int cc = 0; cc < 16; ++cc) {
      float v = tile[ty * 16 + cc][tx];
      s = fmaf(v, v, s);
    }
    red[ty][tx] = s;
  }
  __syncthreads();
  if (threadIdx.x < 64)
    part_sq[((size_t)b * 8 + blockIdx.y) * NP + p0 + threadIdx.x] =
        red[0][threadIdx.x] + red[1][threadIdx.x] + red[2][threadIdx.x] + red[3][threadIdx.x];
  int p = p0 + tx;
  char* dst = (char*)out + (size_t)b * APANEL8
            + (uint32_t)(p >> 4) * 512u + (uint32_t)(p & 15) * 8u;
#pragma unroll
  for (int q = ty; q < 8; q += 4) {
    int c_local = q * 8, c_global = c0 + c_local;
    float f[8];
#pragma unroll
    for (int e = 0; e < 8; ++e) f[e] = tile[c_local + e][tx];
    int lo = 0, hi = 0;
    lo = __builtin_amdgcn_cvt_pk_fp8_f32(f[0], f[1], lo, false);
    lo = __builtin_amdgcn_cvt_pk_fp8_f32(f[2], f[3], lo, true);
    hi = __builtin_amdgcn_cvt_pk_fp8_f32(f[4], f[5], hi, false);
    hi = __builtin_amdgcn_cvt_pk_fp8_f32(f[6], f[7], hi, true);
    union { int i2[2]; long l; } u; u.i2[0] = lo; u.i2[1] = hi;
    uint32_t kt = (uint32_t)c_global >> 5, gg = ((uint32_t)c_global >> 3) & 3u;
    *(long*)(dst + kt * ATILE8 + gg * 128u) = u.l;
  }
}

// ---------------- K2b: inva[b][p] = rsqrt(sum of 8 chunk partials) ----------------
__global__ void inva_kernel(const float* __restrict__ part_sq, float* __restrict__ inva) {
  int idx = blockIdx.x * 256 + threadIdx.x;   // 32*576 = 18,432
  if (idx >= NB * NP) return;
  int b = idx / NP, p = idx - b * NP;
  float s = 0.f;
#pragma unroll
  for (int k = 0; k < 8; ++k) s += part_sq[((size_t)b * 8 + k) * NP + p];
  inva[idx] = rsqrtf(fmaxf(s, 1e-24f));
}

// ---------------- K3: fused pack + GEMM + softmax-reduction (r13 core, UNCHANGED) ----
// Only change vs r19: epilogue multiplies by per-row inva (plain loads after the
// asm core has fully drained at vmcnt(0) -- no interaction with the counted FIFO).
__global__ __launch_bounds__(512, 2)
void affinity_kernel(const uint8_t* __restrict__ A2,
                     const float* __restrict__ x,
                     const float* __restrict__ inva,
                     float* __restrict__ partials) {
  const int bid = blockIdx.x;
  const int T = (bid & 7) * 128 + (bid >> 3);   // bijective XCD swizzle (1024 = 8*128)
  const int b = T >> 5, jc = T & 31;
  const int tid = threadIdx.x, lane = tid & 63, w = tid >> 6;
  const int wm = w & 3, wn = w >> 2;
  const int g = lane >> 4, l15 = lane & 15;
  const int sg = tid >> 7, jloc = tid & 127;

  __shared__ __align__(16) char Bsh[8192];   // 2 x [32k x 128j] fp8, fragment layout
  __shared__ float sqx[4][128];
  __shared__ float invd[128];

  const uint64_t sA = (uint64_t)(uintptr_t)A2;
  const uint64_t sX = (uint64_t)(uintptr_t)x;

  const uint32_t voffX0 = (uint32_t)((b * NC + sg * 8) * NN + jc * 128 + jloc) * 4u;
  uint32_t voffA[9];
#pragma unroll
  for (int mi = 0; mi < 9; ++mi)
    voffA[mi] = (uint32_t)b * APANEL8 + (uint32_t)(wm * 9 + mi) * 512u
              + (uint32_t)lane * 8u;

  const uint32_t wrbase = (uint32_t)(uintptr_t)(&Bsh[0])
                        + (uint32_t)sg * 1024u + (uint32_t)jloc * 8u;

  floatx4 acc[9][4];
#pragma unroll
  for (int mi = 0; mi < 9; ++mi)
#pragma unroll
    for (int q = 0; q < 4; ++q) acc[mi][q] = (floatx4){0.f, 0.f, 0.f, 0.f};

  float GA[8], GB[8];
  long af[9];
  float sq = 0.f;

  auto issueX = [&](int kt, float (&G)[8]) {
#pragma unroll
    for (int e = 0; e < 8; ++e)
      GLOAD_F32(G[e], voffX0 + (uint32_t)kt * 524288u + (uint32_t)e * 16384u, sX);
  };
  auto issueA = [&](int kt) {
#pragma unroll
    for (int mi = 0; mi < 9; ++mi)
      GLOAD_B64(af[mi], voffA[mi] + (uint32_t)kt * ATILE8, sA);
  };
  auto cvtW = [&](float (&G)[8], uint32_t bufoff) {
#pragma unroll
    for (int e = 0; e < 8; ++e) sq = fmaf(G[e], G[e], sq);
    int lo = 0, hi = 0;
    lo = __builtin_amdgcn_cvt_pk_fp8_f32(G[0], G[1], lo, false);
    lo = __builtin_amdgcn_cvt_pk_fp8_f32(G[2], G[3], lo, true);
    hi = __builtin_amdgcn_cvt_pk_fp8_f32(G[4], G[5], hi, false);
    hi = __builtin_amdgcn_cvt_pk_fp8_f32(G[6], G[7], hi, true);
    union { int i2[2]; long l; } u; u.i2[0] = lo; u.i2[1] = hi;
    DSWRITE_B64(wrbase + bufoff, u.l);
  };
  auto mfmaStep = [&](uint32_t bufoff) {
#pragma unroll
    for (int q = 0; q < 4; ++q) {
      long bf = *(const long*)(Bsh + bufoff + (uint32_t)g * 1024u
                               + (uint32_t)(wn * 64 + q * 16 + l15) * 8u);
#pragma unroll
      for (int mi = 0; mi < 9; ++mi)
        acc[mi][q] = __builtin_amdgcn_mfma_f32_16x16x32_fp8_fp8(af[mi], bf, acc[mi][q], 0, 0, 0);
    }
  };

  // ---- prologue: X0->GA, X1->GB, A0->af; buf0 = X0 ----
  issueX(0, GA);
  issueX(1, GB);
  issueA(0);
  WAIT_VMCNT(17); SCHEDBAR();     // X0 home; queue: X1[8] A0[9] = 17
  cvtW(GA, 0u);
  WAIT_LGKM0;
  SBAR();

  // ---- main loop: steps 0..13 (x2 unroll) ----
#pragma unroll 1
  for (int kt = 0; kt < 14; kt += 2) {
    issueX(kt + 2, GA);           // queue: X(kt+1)8 A(kt)9 X(kt+2)8 = 25
    WAIT_VMCNT(8); SCHEDBAR();    // X(kt+1)+A(kt) home; X(kt+2) in flight
    mfmaStep(0u);
    issueA(kt + 1);               // queue: X(kt+2)8 A(kt+1)9 = 17
    cvtW(GB, 4096u);
    WAIT_LGKM0;
    SBAR();
    issueX(kt + 3, GB);
    WAIT_VMCNT(8); SCHEDBAR();
    mfmaStep(4096u);
    issueA(kt + 2);
    cvtW(GA, 0u);
    WAIT_LGKM0;
    SBAR();
  }
  // ---- step 14: queue [X15(8), A14(9)] ----
  WAIT_VMCNT(0); SCHEDBAR();      // X15 + A14 home
  mfmaStep(0u);
  issueA(15);
  cvtW(GB, 4096u);
  WAIT_LGKM0;
  SBAR();
  // ---- step 15 ----
  WAIT_VMCNT(0); SCHEDBAR();      // A15 home
  mfmaStep(4096u);

  // ---- dst inv-norms (columns) ----
  sqx[sg][jloc] = sq;
  __syncthreads();
  if (tid < 128)
    invd[tid] = rsqrtf(fmaxf(sqx[0][tid] + sqx[1][tid] + sqx[2][tid] + sqx[3][tid],
                             1e-24f)) * LOG2E;
  __syncthreads();

  // ---- epilogue: exp2 + weighted reduce; row norm (inva) applied here ----
  const int jcol = jc * 2 + wn;   // 64-col unit index for finalize
#pragma unroll
  for (int mi = 0; mi < 9; ++mi) {
    float ia[4];
#pragma unroll
    for (int r = 0; r < 4; ++r)
      ia[r] = inva[(size_t)b * NP + (wm * 9 + mi) * 16 + g * 4 + r];
    float s4[4] = {0.f, 0.f, 0.f, 0.f}, sx4[4] = {0.f, 0.f, 0.f, 0.f};
#pragma unroll
    for (int q = 0; q < 4; ++q) {
      float ivq = invd[wn * 64 + q * 16 + l15];
      float cx = (float)(q * 16 + l15) + 0.5f;
#pragma unroll
      for (int r = 0; r < 4; ++r) {
        float p = exp2f(acc[mi][q][r] * ivq * ia[r]);
        s4[r] += p;
        sx4[r] = fmaf(p, cx, sx4[r]);
      }
    }
#pragma unroll
    for (int r = 0; r < 4; ++r) {
#pragma unroll
      for (int m = 1; m < 16; m <<= 1) {
        s4[r] += __shfl_xor(s4[r], m);
        sx4[r] += __shfl_xor(sx4[r], m);
      }
    }
    if (l15 == 0) {
#pragma unroll
      for (int r = 0; r < 4; ++r) {
        int row = (wm * 9 + mi) * 16 + g * 4 + r;
        float2 o2 = make_float2(s4[r], sx4[r]);
        *(float2*)(partials + ((size_t)(b * NP + row) * 64 + jcol) * 2) = o2;
      }
    }
  }
}

// ---------------- K4a: wave-parallel per-row softmax reduce ----------------
// 128 blocks = 32 b x 4 row-chunks of 144; 4 waves x 36 rows each.
// Per row: 64 lanes read one float2 each (512 B coalesced), shfl_xor reduce.
__global__ void finalize1_kernel(const float* __restrict__ partials,
                                 float* __restrict__ cpart) {
  const int blk = blockIdx.x;
  const int b = blk >> 2, rc = blk & 3;
  const int lane = threadIdx.x & 63, w = threadIdx.x >> 6;
  float ax = 0.f, ay = 0.f;
#pragma unroll 1
  for (int rr = 0; rr < 36; ++rr) {
    int row = rc * 144 + w * 36 + rr;
    float2 v = *(const float2*)(partials + ((size_t)(b * NP + row) * 64 + lane) * 2);
    float ss = v.x, sxx = v.y;
    float sy = ss * ((float)lane + 0.5f);
#pragma unroll
    for (int m = 1; m < 64; m <<= 1) {
      ss += __shfl_xor(ss, m);
      sxx += __shfl_xor(sxx, m);
      sy += __shfl_xor(sy, m);
    }
    if (lane == 0) { ax += sxx / ss; ay += sy / ss; }
  }
  __shared__ float r1[4], r2[4];
  if (lane == 0) { r1[w] = ax; r2[w] = ay; }
  __syncthreads();
  if (threadIdx.x == 0) {
    cpart[(b * 4 + rc) * 2 + 0] = r1[0] + r1[1] + r1[2] + r1[3];
    cpart[(b * 4 + rc) * 2 + 1] = r2[0] + r2[1] + r2[2] + r2[3];
  }
}

// ---------------- K4b: bbox ----------------
__global__ void finalize2_kernel(const float* __restrict__ cpart, float* __restrict__ out) {
  int b = threadIdx.x;
  if (b >= NB) return;
  float cx = 0.f, cy = 0.f;
#pragma unroll
  for (int rc = 0; rc < 4; ++rc) {
    cx += cpart[(b * 4 + rc) * 2 + 0];
    cy += cpart[(b * 4 + rc) * 2 + 1];
  }
  cx /= (float)NP; cy /= (float)NP;
  float l = fmaxf(cx - 12.f, 0.f);
  float tp = fmaxf(cy - 12.f, 0.f);
  out[b * 4 + 0] = l;
  out[b * 4 + 1] = tp;
  out[b * 4 + 2] = fminf(l + 24.f, 64.f);
  out[b * 4 + 3] = fminf(tp + 24.f, 64.f);
}

extern "C" void kernel_launch(void* const* d_in, const int* in_sizes, int n_in,
                              void* d_out, int out_size, void* d_ws, size_t ws_size,
                              hipStream_t stream) {
  const float* patch_x = (const float*)d_in[0];
  const float* x = (const float*)d_in[1];
  float* out = (float*)d_out;
  char* ws = (char*)d_ws;

  uint8_t* A2 = (uint8_t*)(ws + 0);                   //  9,437,184 B (fp8, raw)
  float* part_sq = (float*)(ws + 9437184);            //    589,824 B
  float* inva = (float*)(ws + 10027008);              //     73,728 B
  float* partials = (float*)(ws + 10100736);          //  9,437,184 B
  float* cpart = (float*)(ws + 19537920);             //      1,024 B

  transpose_kernel<<<dim3(NP / 64, NC / 64, NB), 256, 0, stream>>>(patch_x, A2, part_sq, NP);
  inva_kernel<<<dim3((NB * NP + 255) / 256), 256, 0, stream>>>(part_sq, inva);
  affinity_kernel<<<dim3(1024), 512, 0, stream>>>(A2, x, inva, partials);
  finalize1_kernel<<<dim3(128), 256, 0, stream>>>(partials, cpart);
  finalize2_kernel<<<dim3(1), 64, 0, stream>>>(cpart, out);
}